// Round 4
// baseline (7193.960 us; speedup 1.0000x reference)
//
#include <hip/hip_runtime.h>

// LSTM decoder B=2048, Z=64, A=8, H=512, T=64.
// Persistent cooperative kernel: 256 WGs (16 nt x 16 bt), flag-synced clusters.
// gates = [h | z] @ [W_hh | W_ih_z]^T + bias ; bf16 MFMA 16x16x32.

#define HID   512
#define TSTEP 64
#define KCAT  576

typedef __attribute__((ext_vector_type(8))) short bf16x8;
typedef __attribute__((ext_vector_type(4))) float f32x4;

__device__ inline unsigned short f2bf(float f) {
  unsigned int u = __builtin_bit_cast(unsigned int, f);
  unsigned int r = (u + 0x7fffu + ((u >> 16) & 1u)) >> 16;
  return (unsigned short)r;
}
__device__ inline float bf2f(unsigned short u) {
  unsigned int x = ((unsigned int)u) << 16;
  return __builtin_bit_cast(float, x);
}
__device__ inline float sigm(float x) { return 1.0f / (1.0f + __expf(-x)); }
__device__ inline float tanh_f(float x) { return 1.0f - 2.0f / (__expf(2.0f * x) + 1.0f); }

__device__ inline void gl16(const unsigned short* g, unsigned short* l) {
  __builtin_amdgcn_global_load_lds(
      (const __attribute__((address_space(1))) unsigned int*)g,
      (__attribute__((address_space(3))) unsigned int*)l, 16, 0, 0);
}

// ---- prep: W_cat[n][0..575] = [W_hh[n][:] | W_ih[n][8..71]] bf16 ----
__global__ void k_prep_w(const float* __restrict__ whh, const float* __restrict__ wih,
                         unsigned short* __restrict__ wcat) {
  int c = blockIdx.x * 256 + threadIdx.x;
  if (c >= 2048 * 72) return;
  int n = c / 72, kc = (c % 72) * 8;
  unsigned short u[8];
#pragma unroll
  for (int e = 0; e < 8; ++e) {
    int k = kc + e;
    float v = (k < 512) ? whh[(size_t)n * 512 + k] : wih[(size_t)n * 72 + 8 + (k - 512)];
    u[e] = f2bf(v);
  }
  *(bf16x8*)&wcat[(size_t)n * KCAT + kc] = *(bf16x8*)u;
}

__global__ void k_prep_zb(const float* __restrict__ z, const float* __restrict__ bih,
                          const float* __restrict__ bhh, unsigned short* __restrict__ zbf,
                          float* __restrict__ bias) {
  int c = blockIdx.x * 256 + threadIdx.x;
  if (c < 16384) {
    int row = c >> 3, kc = (c & 7) * 8;
    unsigned short u[8];
#pragma unroll
    for (int e = 0; e < 8; ++e) u[e] = f2bf(z[(size_t)row * 64 + kc + e]);
    *(bf16x8*)&zbf[(size_t)row * 64 + kc] = *(bf16x8*)u;
  } else if (c < 16384 + 2048) {
    int n = c - 16384;
    bias[n] = bih[n] + bhh[n];
  }
}

__global__ void k_zero(int* __restrict__ flags) {
  int g = blockIdx.x * 256 + threadIdx.x;
  if (g < TSTEP * 16) flags[g] = 0;
}

struct P {
  const unsigned short *wcat, *zbf;
  const float *bias, *wout;
  unsigned short *h0, *h1;
  float* part;
  int* flags;
};

__device__ inline void aload(bf16x8& d00, bf16x8& d01, bf16x8& d10, bf16x8& d11,
                             const unsigned short* hrd, const unsigned short* zb,
                             int kk, int arow0, int q8) {
  if (kk < 8) {
    const unsigned short* ap = hrd + (size_t)arow0 * HID + kk * 64 + q8 * 8;
    d00 = *(const bf16x8*)ap;
    d01 = *(const bf16x8*)(ap + 16 * HID);
    d10 = *(const bf16x8*)(ap + 32);
    d11 = *(const bf16x8*)(ap + 16 * HID + 32);
  } else {
    const unsigned short* ap = zb + (size_t)arow0 * 64 + q8 * 8;
    d00 = *(const bf16x8*)ap;
    d01 = *(const bf16x8*)(ap + 16 * 64);
    d10 = *(const bf16x8*)(ap + 32);
    d11 = *(const bf16x8*)(ap + 16 * 64 + 32);
  }
}

__global__ __launch_bounds__(512, 2) void k_persist(P p) {
  __shared__ unsigned short Bb[2][128 * 64];
  __shared__ unsigned short hO[128 * 34];
  __shared__ float wo[8 * 33];

  const int bid = blockIdx.x;
  const int nt = bid & 15, bt = bid >> 4;
  const int tid = threadIdx.x;
  const int lane = tid & 63;
  const int wv = tid >> 6;
  const int mq = wv >> 1, nh = wv & 1;
  const int cl = lane & 15, q8 = lane >> 4;
  const int b0 = bt * 128;
  const int j0 = nt * 32;
  const int col = j0 + nh * 16 + cl;
  const int arow0 = b0 + mq * 32 + cl;

  if (tid < 256) { int a = tid >> 5, j = tid & 31; wo[a * 33 + j] = p.wout[(size_t)a * HID + j0 + j]; }

  // W staging addresses (XOR-swizzled source, linear LDS dest)
  const int r1 = tid >> 3, qq = tid & 7;
  const int n1 = (r1 >> 5) * HID + j0 + (r1 & 31);
  const int n2 = ((r1 + 64) >> 5) * HID + j0 + ((r1 + 64) & 31);
  const unsigned short* wsrc1 = p.wcat + (size_t)n1 * KCAT + (qq ^ (r1 & 7)) * 8;
  const unsigned short* wsrc2 = p.wcat + (size_t)n2 * KCAT + (qq ^ (r1 & 7)) * 8;

#define STAGE(BUF, CHUNK) do { unsigned short* lb = &Bb[BUF][wv * 512]; \
    gl16(wsrc1 + (CHUNK) * 64, lb); gl16(wsrc2 + (CHUNK) * 64, lb + 4096); } while (0)

  float bias_r[4];
#pragma unroll
  for (int g4 = 0; g4 < 4; ++g4) bias_r[g4] = p.bias[g4 * HID + col];

  f32x4 c0 = {0, 0, 0, 0}, c1 = {0, 0, 0, 0};

  int cur = 0;
  STAGE(0, 8);            // t=0 uses only the z-chunk (kk=8)
  __syncthreads();

  for (int t = 0; t < TSTEP; ++t) {
    const unsigned short* hrd = (t & 1) ? p.h0 : p.h1;
    unsigned short* hwr = (t & 1) ? p.h1 : p.h0;

    if (t > 0) {
      if (tid == 0) {
        while (__hip_atomic_load(&p.flags[(t - 1) * 16 + bt], __ATOMIC_ACQUIRE,
                                 __HIP_MEMORY_SCOPE_AGENT) < 16)
          __builtin_amdgcn_s_sleep(1);
      }
      __syncthreads();
      __threadfence();     // acquire: invalidate caches so h(t-1) reads are fresh
    }

    f32x4 acc[4][2];
#pragma unroll
    for (int g4 = 0; g4 < 4; ++g4) {
      f32x4 v = {bias_r[g4], bias_r[g4], bias_r[g4], bias_r[g4]};
      acc[g4][0] = v; acc[g4][1] = v;
    }

    const int kk0 = t ? 0 : 8;
    bf16x8 aa00, aa01, aa10, aa11;
    aload(aa00, aa01, aa10, aa11, hrd, p.zbf, kk0, arow0, q8);

    for (int kk = kk0; kk <= 8; ++kk) {
      if (kk < 8) STAGE(cur ^ 1, kk + 1);
      else if (t < TSTEP - 1) STAGE(cur ^ 1, 0);   // cross-step W prefetch

      bf16x8 nn00, nn01, nn10, nn11;
      if (kk < 8) aload(nn00, nn01, nn10, nn11, hrd, p.zbf, kk + 1, arow0, q8);

      const unsigned short* Bl = Bb[cur];
      const int swz0 = (q8 ^ (cl & 7)) * 8;
      const int swz1 = ((4 + q8) ^ (cl & 7)) * 8;
#pragma unroll
      for (int g4 = 0; g4 < 4; ++g4) {
        int rbase = (g4 * 32 + nh * 16 + cl) * 64;
        bf16x8 bf0 = *(const bf16x8*)&Bl[rbase + swz0];
        acc[g4][0] = __builtin_amdgcn_mfma_f32_16x16x32_bf16(aa00, bf0, acc[g4][0], 0, 0, 0);
        acc[g4][1] = __builtin_amdgcn_mfma_f32_16x16x32_bf16(aa01, bf0, acc[g4][1], 0, 0, 0);
        bf16x8 bf1 = *(const bf16x8*)&Bl[rbase + swz1];
        acc[g4][0] = __builtin_amdgcn_mfma_f32_16x16x32_bf16(aa10, bf1, acc[g4][0], 0, 0, 0);
        acc[g4][1] = __builtin_amdgcn_mfma_f32_16x16x32_bf16(aa11, bf1, acc[g4][1], 0, 0, 0);
      }
      __syncthreads();
      cur ^= 1;
      if (kk < 8) { aa00 = nn00; aa01 = nn01; aa10 = nn10; aa11 = nn11; }
    }

    // ---- cell: c in registers; h -> LDS ----
#pragma unroll
    for (int mt = 0; mt < 2; ++mt) {
      f32x4 cold = mt ? c1 : c0;
      f32x4 cnew;
#pragma unroll
      for (int r = 0; r < 4; ++r) {
        float iv = sigm(acc[0][mt][r]);
        float fv = sigm(acc[1][mt][r]);
        float gv = tanh_f(acc[2][mt][r]);
        float ov = sigm(acc[3][mt][r]);
        float cc = fv * cold[r] + iv * gv;
        cnew[r] = cc;
        float hv = ov * tanh_f(cc);
        hO[(mq * 32 + mt * 16 + q8 * 4 + r) * 34 + nh * 16 + cl] = f2bf(hv);
      }
      if (mt) c1 = cnew; else c0 = cnew;
    }
    __syncthreads();   // hO ready

    // ---- h -> global ping-pong (skip on last step) ----
    if (t < TSTEP - 1) {
      int row = tid >> 2, sg = tid & 3;
      unsigned short tmp[8];
#pragma unroll
      for (int e = 0; e < 8; ++e) tmp[e] = hO[row * 34 + sg * 8 + e];
      *(int4*)&hwr[(size_t)(b0 + row) * HID + j0 + sg * 8] = *(int4*)tmp;
    }

    // ---- partial output projection -> part ----
#pragma unroll
    for (int pq = 0; pq < 2; ++pq) {
      int idx = tid * 2 + pq, row = idx >> 3, a = idx & 7;
      float s = 0.0f;
#pragma unroll
      for (int j = 0; j < 32; ++j) s += bf2f(hO[row * 34 + j]) * wo[a * 33 + j];
      p.part[(size_t)nt * 1048576 + (size_t)(b0 + row) * 512 + t * 8 + a] = s;
    }

    if (t < TSTEP - 1) {
      __threadfence();   // release: write back h before signaling
      __syncthreads();
      if (tid == 0)
        __hip_atomic_fetch_add(&p.flags[t * 16 + bt], 1, __ATOMIC_RELEASE,
                               __HIP_MEMORY_SCOPE_AGENT);
    }
  }
#undef STAGE
}

__global__ void k_final(const float* __restrict__ part, const float* __restrict__ bout,
                        float* __restrict__ out) {
  int g = blockIdx.x * 256 + threadIdx.x;
  float s = bout[g & 7];
#pragma unroll
  for (int n = 0; n < 16; ++n) s += part[(size_t)n * 1048576 + g];
  out[g] = s;
}

// ---------------- fallback: round-3 multi-launch path ----------------
__global__ void k_initout(const float* __restrict__ bout, float* __restrict__ out) {
  int g = blockIdx.x * 256 + threadIdx.x;
  out[g] = bout[g & 7];
}

__global__ __launch_bounds__(512, 2) void k_stepA(
    const unsigned short* __restrict__ hprev, unsigned short* __restrict__ hnext,
    const unsigned short* __restrict__ wcat, const unsigned short* __restrict__ zbf,
    const float* __restrict__ bias, float* __restrict__ cst,
    const float* __restrict__ wout, float* __restrict__ dst, int t) {
  __shared__ unsigned short Bb[2][128 * 64];
  __shared__ unsigned short hO[128 * 34];
  __shared__ float wo[8 * 33];

  const int nt = blockIdx.x, bt = blockIdx.y;
  const int tid = threadIdx.x;
  const int lane = tid & 63;
  const int wv = tid >> 6;
  const int mq = wv >> 1, nh = wv & 1;
  const int cl = lane & 15, q8 = lane >> 4;
  const int b0 = bt * 128;
  const int j0 = nt * 32;

  if (tid < 256) { int a = tid >> 5, j = tid & 31; wo[a * 33 + j] = wout[(size_t)a * HID + j0 + j]; }

  const int r1 = tid >> 3, qq = tid & 7;
  const int n1 = (r1 >> 5) * HID + j0 + (r1 & 31);
  const int n2 = ((r1 + 64) >> 5) * HID + j0 + ((r1 + 64) & 31);
  const unsigned short* wsrc1 = wcat + (size_t)n1 * KCAT + (qq ^ (r1 & 7)) * 8;
  const unsigned short* wsrc2 = wcat + (size_t)n2 * KCAT + (qq ^ (r1 & 7)) * 8;

  const int col = j0 + nh * 16 + cl;
  f32x4 acc[4][2];
#pragma unroll
  for (int g4 = 0; g4 < 4; ++g4) {
    float bv = bias[g4 * HID + col];
    f32x4 v = {bv, bv, bv, bv};
    acc[g4][0] = v; acc[g4][1] = v;
  }

  const size_t cbase = (((size_t)bt * 16 + nt) * 512 + tid) * 8;
  f32x4 cold0 = {0, 0, 0, 0}, cold1 = {0, 0, 0, 0};
  if (t > 0) { cold0 = *(const f32x4*)&cst[cbase]; cold1 = *(const f32x4*)&cst[cbase + 4]; }

  const int arow0 = b0 + mq * 32 + cl;
  const int kk0 = (t > 0) ? 0 : 8;
  {
    unsigned short* lb = &Bb[0][wv * 512];
    gl16(wsrc1 + kk0 * 64, lb);
    gl16(wsrc2 + kk0 * 64, lb + 4096);
  }
  __syncthreads();

  bf16x8 aa00, aa01, aa10, aa11;
  aload(aa00, aa01, aa10, aa11, hprev, zbf, kk0, arow0, q8);

  for (int kk = kk0; kk <= 8; ++kk) {
    const int bu = (kk - kk0) & 1;
    if (kk < 8) {
      unsigned short* lb = &Bb[bu ^ 1][wv * 512];
      gl16(wsrc1 + (kk + 1) * 64, lb);
      gl16(wsrc2 + (kk + 1) * 64, lb + 4096);
    }
    bf16x8 nn00, nn01, nn10, nn11;
    if (kk < 8) aload(nn00, nn01, nn10, nn11, hprev, zbf, kk + 1, arow0, q8);

    const unsigned short* Bl = Bb[bu];
    const int swz0 = (q8 ^ (cl & 7)) * 8;
    const int swz1 = ((4 + q8) ^ (cl & 7)) * 8;
#pragma unroll
    for (int g4 = 0; g4 < 4; ++g4) {
      int rbase = (g4 * 32 + nh * 16 + cl) * 64;
      bf16x8 bf0 = *(const bf16x8*)&Bl[rbase + swz0];
      acc[g4][0] = __builtin_amdgcn_mfma_f32_16x16x32_bf16(aa00, bf0, acc[g4][0], 0, 0, 0);
      acc[g4][1] = __builtin_amdgcn_mfma_f32_16x16x32_bf16(aa01, bf0, acc[g4][1], 0, 0, 0);
      bf16x8 bf1 = *(const bf16x8*)&Bl[rbase + swz1];
      acc[g4][0] = __builtin_amdgcn_mfma_f32_16x16x32_bf16(aa10, bf1, acc[g4][0], 0, 0, 0);
      acc[g4][1] = __builtin_amdgcn_mfma_f32_16x16x32_bf16(aa11, bf1, acc[g4][1], 0, 0, 0);
    }
    __syncthreads();
    if (kk < 8) { aa00 = nn00; aa01 = nn01; aa10 = nn10; aa11 = nn11; }
  }

  f32x4 cn0, cn1;
#pragma unroll
  for (int mt = 0; mt < 2; ++mt) {
    f32x4 cold = mt ? cold1 : cold0;
    f32x4 cnew;
#pragma unroll
    for (int r = 0; r < 4; ++r) {
      float iv = sigm(acc[0][mt][r]);
      float fv = sigm(acc[1][mt][r]);
      float gv = tanh_f(acc[2][mt][r]);
      float ov = sigm(acc[3][mt][r]);
      float cc = fv * cold[r] + iv * gv;
      cnew[r] = cc;
      hO[(mq * 32 + mt * 16 + q8 * 4 + r) * 34 + nh * 16 + cl] = f2bf(ov * tanh_f(cc));
    }
    if (mt) cn1 = cnew; else cn0 = cnew;
  }
  *(f32x4*)&cst[cbase] = cn0;
  *(f32x4*)&cst[cbase + 4] = cn1;
  __syncthreads();

  {
    int row = tid >> 2, sg = tid & 3;
    unsigned short tmp[8];
#pragma unroll
    for (int e = 0; e < 8; ++e) tmp[e] = hO[row * 34 + sg * 8 + e];
    *(int4*)&hnext[(size_t)(b0 + row) * HID + j0 + sg * 8] = *(int4*)tmp;
  }

#pragma unroll
  for (int pq = 0; pq < 2; ++pq) {
    int idx = tid * 2 + pq, row = idx >> 3, a = idx & 7;
    float s = 0.0f;
#pragma unroll
    for (int j = 0; j < 32; ++j) s += bf2f(hO[row * 34 + j]) * wo[a * 33 + j];
    atomicAdd(&dst[(size_t)(b0 + row) * 512 + t * 8 + a], s);
  }
}

extern "C" void kernel_launch(void* const* d_in, const int* in_sizes, int n_in,
                              void* d_out, int out_size, void* d_ws, size_t ws_size,
                              hipStream_t stream) {
  const float* z    = (const float*)d_in[0];
  const float* wih  = (const float*)d_in[1];
  const float* whh  = (const float*)d_in[2];
  const float* bih  = (const float*)d_in[3];
  const float* bhh  = (const float*)d_in[4];
  const float* wout = (const float*)d_in[5];
  const float* bout = (const float*)d_in[6];
  float* out = (float*)d_out;

  char* ws = (char*)d_ws;
  unsigned short* wcat = (unsigned short*)(ws);              // 2,359,296
  unsigned short* zbf  = (unsigned short*)(ws + 2359296);    //   262,144
  float* bias          = (float*)(ws + 2621440);             //     8,192
  unsigned short* h0   = (unsigned short*)(ws + 2629632);    // 2,097,152
  unsigned short* h1   = (unsigned short*)(ws + 4726784);    // 2,097,152
  int* flags           = (int*)(ws + 6823936);               //     4,096
  float* cst           = (float*)(ws + 6828032);             // 4,194,304 (fallback only)
  float* part          = (float*)(ws + 11022336);            // 67,108,864
  const bool use_part = ws_size >= 11022336ull + 67108864ull;

  k_prep_w<<<dim3(576), dim3(256), 0, stream>>>(whh, wih, wcat);
  k_prep_zb<<<dim3(72), dim3(256), 0, stream>>>(z, bih, bhh, zbf, bias);

  if (use_part) {
    k_zero<<<dim3(4), dim3(256), 0, stream>>>(flags);
    P pp;
    pp.wcat = wcat; pp.zbf = zbf; pp.bias = bias; pp.wout = wout;
    pp.h0 = h0; pp.h1 = h1; pp.part = part; pp.flags = flags;
    void* args[] = {&pp};
    hipError_t e = hipLaunchCooperativeKernel((const void*)k_persist, dim3(256), dim3(512),
                                              args, 0, stream);
    if (e == hipSuccess) {
      k_final<<<dim3(4096), dim3(256), 0, stream>>>(part, bout, out);
      return;
    }
  }

  // ---- fallback: multi-launch, atomic output accumulation ----
  k_initout<<<dim3(4096), dim3(256), 0, stream>>>(bout, out);
  for (int t = 0; t < TSTEP; ++t) {
    const unsigned short* hp = (t & 1) ? h0 : h1;
    unsigned short* hn = (t & 1) ? h1 : h0;
    k_stepA<<<dim3(16, 16), dim3(512), 0, stream>>>(hp, hn, wcat, zbf, bias, cst, wout, out, t);
  }
}

// Round 5
// 1389.014 us; speedup vs baseline: 5.1792x; 5.1792x over previous
//
#include <hip/hip_runtime.h>

// LSTM decoder B=2048, Z=64, A=8, H=512, T=64. Multi-launch (kernel-boundary
// coherence), one launch per step. gates = [h | z] @ [W_hh | W_ih_z]^T + bias.
// bf16 MFMA 16x16x32. Wave = 64 batch x 16 j x 4 gates (4Mx4G frags, 0.5 LDS
// reads/MFMA). A direct from global (L2), B via global_load_lds + XOR swizzle.

#define HID   512
#define TSTEP 64
#define KCAT  576

typedef __attribute__((ext_vector_type(8))) short bf16x8;
typedef __attribute__((ext_vector_type(4))) float f32x4;

__device__ inline unsigned short f2bf(float f) {
  unsigned int u = __builtin_bit_cast(unsigned int, f);
  unsigned int r = (u + 0x7fffu + ((u >> 16) & 1u)) >> 16;
  return (unsigned short)r;
}
__device__ inline float sigm(float x) { return 1.0f / (1.0f + __expf(-x)); }
__device__ inline float tanh_f(float x) { return 1.0f - 2.0f / (__expf(2.0f * x) + 1.0f); }

__device__ inline void gl16(const unsigned short* g, unsigned short* l) {
  __builtin_amdgcn_global_load_lds(
      (const __attribute__((address_space(1))) unsigned int*)g,
      (__attribute__((address_space(3))) unsigned int*)l, 16, 0, 0);
}

// ---- prep: W_cat[n][0..575] = [W_hh[n][:] | W_ih[n][8..71]] bf16 ----
__global__ void k_prep_w(const float* __restrict__ whh, const float* __restrict__ wih,
                         unsigned short* __restrict__ wcat) {
  int c = blockIdx.x * 256 + threadIdx.x;
  if (c >= 2048 * 72) return;
  int n = c / 72, kc = (c % 72) * 8;
  unsigned short u[8];
#pragma unroll
  for (int e = 0; e < 8; ++e) {
    int k = kc + e;
    float v = (k < 512) ? whh[(size_t)n * 512 + k] : wih[(size_t)n * 72 + 8 + (k - 512)];
    u[e] = f2bf(v);
  }
  *(bf16x8*)&wcat[(size_t)n * KCAT + kc] = *(bf16x8*)u;
}

__global__ void k_prep_zb(const float* __restrict__ z, const float* __restrict__ bih,
                          const float* __restrict__ bhh, unsigned short* __restrict__ zbf,
                          float* __restrict__ bias) {
  int c = blockIdx.x * 256 + threadIdx.x;
  if (c < 16384) {
    int row = c >> 3, kc = (c & 7) * 8;
    unsigned short u[8];
#pragma unroll
    for (int e = 0; e < 8; ++e) u[e] = f2bf(z[(size_t)row * 64 + kc + e]);
    *(bf16x8*)&zbf[(size_t)row * 64 + kc] = *(bf16x8*)u;
  } else if (c < 16384 + 2048) {
    int n = c - 16384;
    bias[n] = bih[n] + bhh[n];
  }
}

__global__ void k_initout(const float* __restrict__ bout, float* __restrict__ out) {
  int g = blockIdx.x * 256 + threadIdx.x;
  out[g] = bout[g & 7];
}

// A-fragment loads: 4 M-frags x 2 ks, direct from global (h or z)
__device__ inline void aload8(bf16x8 d[8], const unsigned short* hrd,
                              const unsigned short* zb, int kk, int arow,
                              int cl, int q8) {
  if (kk < 8) {
    const unsigned short* p = hrd + (size_t)(arow + cl) * HID + kk * 64 + q8 * 8;
#pragma unroll
    for (int m = 0; m < 4; ++m) {
      d[m * 2 + 0] = *(const bf16x8*)(p + m * 16 * HID);
      d[m * 2 + 1] = *(const bf16x8*)(p + m * 16 * HID + 32);
    }
  } else {
    const unsigned short* p = zb + (size_t)(arow + cl) * 64 + q8 * 8;
#pragma unroll
    for (int m = 0; m < 4; ++m) {
      d[m * 2 + 0] = *(const bf16x8*)(p + m * 16 * 64);
      d[m * 2 + 1] = *(const bf16x8*)(p + m * 16 * 64 + 32);
    }
  }
}

// ---- one step. grid (nt 16, bt 16), 256 thr (4 waves). ----
// WG tile: 128 batch x 32 j x 4 gates. Wave: 64 batch x 16 j x 4 gates.
template <int USE_PART>
__global__ __launch_bounds__(256, 1) void k_step(
    const unsigned short* __restrict__ hprev, unsigned short* __restrict__ hnext,
    const unsigned short* __restrict__ wcat, const unsigned short* __restrict__ zbf,
    const float* __restrict__ bias, float* __restrict__ cst,
    const float* __restrict__ wout, float* __restrict__ dst, int t) {
  __shared__ unsigned short Bb[2][128 * 64];   // B chunk dbuf, 16 KB each
  __shared__ unsigned short hO[128 * 40];      // h tile, 80B row stride (16B-aligned)
  __shared__ unsigned short wo16[16 * 32];     // W_out slice bf16, rows 8..15 zero

  const int nt = blockIdx.x, bt = blockIdx.y;
  const int tid = threadIdx.x;
  const int lane = tid & 63;
  const int wv = tid >> 6;                     // 0..3
  const int jh = wv & 1, mg = wv >> 1;
  const int cl = lane & 15, q8 = lane >> 4;
  const int b0 = bt * 128, j0 = nt * 32;
  const int arow = b0 + mg * 64;

  for (int i = tid; i < 512; i += 256) {
    int a = i >> 5, j = i & 31;
    wo16[i] = (a < 8) ? f2bf(wout[(size_t)a * HID + j0 + j]) : (unsigned short)0;
  }

  // B staging: thread covers 4 (row, seg) slots; source XOR-pre-swizzled
  const unsigned short* wsrc[4];
#pragma unroll
  for (int c = 0; c < 4; ++c) {
    int r = c * 32 + wv * 8 + (lane >> 3);
    int s = lane & 7;
    int n = (r >> 5) * HID + j0 + (r & 31);
    wsrc[c] = wcat + (size_t)n * KCAT + (s ^ (r & 7)) * 8;
  }
#define STAGE(BUF, CHUNK) do { \
  _Pragma("unroll") for (int c = 0; c < 4; ++c) \
    gl16(wsrc[c] + (CHUNK) * 64, &Bb[BUF][c * 2048 + wv * 512]); } while (0)

  // acc init = bias
  f32x4 acc[4][4];
#pragma unroll
  for (int g = 0; g < 4; ++g) {
    float bv = bias[g * HID + j0 + jh * 16 + cl];
    f32x4 v = {bv, bv, bv, bv};
#pragma unroll
    for (int m = 0; m < 4; ++m) acc[g][m] = v;
  }

  // c state: thread-contiguous 16 f32
  const size_t cbase = (((size_t)bt * 16 + nt) * 256 + tid) * 16;
  f32x4 cc[4];
#pragma unroll
  for (int m = 0; m < 4; ++m) cc[m] = (f32x4){0, 0, 0, 0};
  if (t > 0) {
#pragma unroll
    for (int m = 0; m < 4; ++m) cc[m] = *(const f32x4*)&cst[cbase + m * 4];
  }

  const int kk0 = t ? 0 : 8;                   // t=0: only z chunk
  STAGE(0, kk0);
  bf16x8 aa[8], nn[8];
  aload8(aa, hprev, zbf, kk0, arow, cl, q8);
  __syncthreads();

  for (int kk = kk0; kk <= 8; ++kk) {
    const int bu = (kk - kk0) & 1;
    if (kk < 8) {
      STAGE(bu ^ 1, kk + 1);
      aload8(nn, hprev, zbf, kk + 1, arow, cl, q8);
    }
    const unsigned short* Bl = Bb[bu];
#pragma unroll
    for (int ks = 0; ks < 2; ++ks) {
#pragma unroll
      for (int g = 0; g < 4; ++g) {
        int rb = (g * 32 + jh * 16 + cl) * 64;
        bf16x8 bf = *(const bf16x8*)&Bl[rb + ((ks * 4 + q8) ^ (cl & 7)) * 8];
#pragma unroll
        for (int m = 0; m < 4; ++m)
          acc[g][m] = __builtin_amdgcn_mfma_f32_16x16x32_bf16(aa[m * 2 + ks], bf, acc[g][m], 0, 0, 0);
      }
    }
    __syncthreads();
    if (kk < 8) {
#pragma unroll
      for (int i = 0; i < 8; ++i) aa[i] = nn[i];
    }
  }

  // ---- cell: c in registers via cst; h -> LDS ----
#pragma unroll
  for (int m = 0; m < 4; ++m) {
    f32x4 cn;
#pragma unroll
    for (int r = 0; r < 4; ++r) {
      float iv = sigm(acc[0][m][r]);
      float fv = sigm(acc[1][m][r]);
      float gv = tanh_f(acc[2][m][r]);
      float ov = sigm(acc[3][m][r]);
      float cv = fv * cc[m][r] + iv * gv;
      cn[r] = cv;
      hO[(mg * 64 + m * 16 + q8 * 4 + r) * 40 + jh * 16 + cl] = f2bf(ov * tanh_f(cv));
    }
    *(f32x4*)&cst[cbase + m * 4] = cn;
  }
  __syncthreads();

  // ---- h -> global ping-pong (32B per thread, coalesced) ----
  if (t < TSTEP - 1) {
    int row = tid >> 1, hf = tid & 1;
    unsigned short tmp[16];
#pragma unroll
    for (int e = 0; e < 16; ++e) tmp[e] = hO[row * 40 + hf * 16 + e];
    *(int4*)&hnext[(size_t)(b0 + row) * HID + j0 + hf * 16] = *(int4*)&tmp[0];
    *(int4*)&hnext[(size_t)(b0 + row) * HID + j0 + hf * 16 + 8] = *(int4*)&tmp[8];
  }

  // ---- output projection via MFMA: (16 batch x 8 a) per fragment ----
  {
    bf16x8 bw = *(const bf16x8*)&wo16[cl * 32 + q8 * 8];
#pragma unroll
    for (int f = 0; f < 2; ++f) {
      int m2 = wv * 2 + f;                     // 16-row block 0..7
      bf16x8 ah = *(const bf16x8*)&hO[(m2 * 16 + cl) * 40 + q8 * 8];
      f32x4 pr = {0, 0, 0, 0};
      pr = __builtin_amdgcn_mfma_f32_16x16x32_bf16(ah, bw, pr, 0, 0, 0);
      if (cl < 8) {
#pragma unroll
        for (int r = 0; r < 4; ++r) {
          int row = m2 * 16 + q8 * 4 + r;
          if (USE_PART)
            dst[(size_t)nt * 1048576 + (size_t)(b0 + row) * 512 + t * 8 + cl] = pr[r];
          else
            atomicAdd(&dst[(size_t)(b0 + row) * 512 + t * 8 + cl], pr[r]);
        }
      }
    }
  }
#undef STAGE
}

__global__ void k_final(const float* __restrict__ part, const float* __restrict__ bout,
                        float* __restrict__ out) {
  int g = blockIdx.x * 256 + threadIdx.x;      // (b*64+t)*8+a
  float s = bout[g & 7];
#pragma unroll
  for (int n = 0; n < 16; ++n) s += part[(size_t)n * 1048576 + g];
  out[g] = s;
}

extern "C" void kernel_launch(void* const* d_in, const int* in_sizes, int n_in,
                              void* d_out, int out_size, void* d_ws, size_t ws_size,
                              hipStream_t stream) {
  const float* z    = (const float*)d_in[0];
  const float* wih  = (const float*)d_in[1];
  const float* whh  = (const float*)d_in[2];
  const float* bih  = (const float*)d_in[3];
  const float* bhh  = (const float*)d_in[4];
  const float* wout = (const float*)d_in[5];
  const float* bout = (const float*)d_in[6];
  float* out = (float*)d_out;

  char* ws = (char*)d_ws;
  unsigned short* wcat = (unsigned short*)(ws);              // 2,359,296
  unsigned short* zbf  = (unsigned short*)(ws + 2359296);    //   262,144
  float* bias          = (float*)(ws + 2621440);             //     8,192
  unsigned short* h0   = (unsigned short*)(ws + 2629632);    // 2,097,152
  unsigned short* h1   = (unsigned short*)(ws + 4726784);    // 2,097,152
  float* cst           = (float*)(ws + 6823936);             // 4,194,304
  float* part          = (float*)(ws + 11018240);            // 67,108,864
  const bool use_part = ws_size >= 11018240ull + 67108864ull;

  k_prep_w<<<dim3(576), dim3(256), 0, stream>>>(whh, wih, wcat);
  k_prep_zb<<<dim3(72), dim3(256), 0, stream>>>(z, bih, bhh, zbf, bias);
  if (!use_part) k_initout<<<dim3(4096), dim3(256), 0, stream>>>(bout, out);

  for (int t = 0; t < TSTEP; ++t) {
    const unsigned short* hp = (t & 1) ? h0 : h1;
    unsigned short* hn = (t & 1) ? h1 : h0;
    if (use_part)
      k_step<1><<<dim3(16, 16), dim3(256), 0, stream>>>(hp, hn, wcat, zbf, bias, cst, wout, part, t);
    else
      k_step<0><<<dim3(16, 16), dim3(256), 0, stream>>>(hp, hn, wcat, zbf, bias, cst, wout, out, t);
  }
  if (use_part) k_final<<<dim3(4096), dim3(256), 0, stream>>>(part, bout, out);
}